// Round 5
// baseline (220.766 us; speedup 1.0000x reference)
//
#include <hip/hip_runtime.h>
#include <math.h>

// One thread handles 8 consecutive pixels of one camera n.
// Inputs fp32; output fp32. in_sizes are ELEMENT counts (in_sizes[0]=512 -> N=32).
// out layout: [ray_origins (N*M*3 f32)] [ray_dirs (N*M*3 f32)]
__global__ __launch_bounds__(256) void ray_sampler_kernel(
    const float* __restrict__ c2w,   // N*16 fp32, row-major 4x4
    const float* __restrict__ intr,  // N*9 fp32, row-major 3x3
    float* __restrict__ out,
    int M, int res, int blocks_per_n, size_t dir_off)
{
    const int n = blockIdx.x / blocks_per_n;
    const int g = (blockIdx.x % blocks_per_n) * blockDim.x + threadIdx.x;
    const int m0 = g * 8;
    if (m0 >= M) return;

    const float* C = c2w + n * 16;
    const float* K = intr + n * 9;

    const float r00 = C[0], r01 = C[1], r02 = C[2];
    const float ox  = C[3];
    const float r10 = C[4], r11 = C[5], r12 = C[6];
    const float oy  = C[7];
    const float r20 = C[8], r21 = C[9], r22 = C[10];
    const float oz  = C[11];

    const float fx = K[0], sk = K[1], cx = K[2];
    const float fy = K[4], cy = K[5];

    const float inv_fx  = 1.0f / fx;
    const float inv_fy  = 1.0f / fy;
    const float inv_res = 1.0f / (float)res;

    const int i  = m0 / res;          // row (y); 8 pixels stay in one row (res % 8 == 0)
    const int j0 = m0 - i * res;      // starting column (x)

    const float y_cam  = ((float)i + 0.5f) * inv_res;
    const float ycc    = (y_cam - cy) * inv_fy;
    const float y_lift = -ycc;
    const float xc_off = -cx - sk * ycc;   // x_lift = (x_cam + xc_off) * inv_fx

    // x-independent part of the un-normalized direction (translation cancels)
    const float base0 = r01 * y_lift - r02;
    const float base1 = r11 * y_lift - r12;
    const float base2 = r21 * y_lift - r22;

    float dbuf[24];
    #pragma unroll
    for (int k = 0; k < 8; ++k) {
        const float x_cam  = ((float)(j0 + k) + 0.5f) * inv_res;
        const float x_lift = (x_cam + xc_off) * inv_fx;
        const float dx = fmaf(r00, x_lift, base0);
        const float dy = fmaf(r10, x_lift, base1);
        const float dz = fmaf(r20, x_lift, base2);
        const float s   = fmaf(dx, dx, fmaf(dy, dy, dz * dz));
        const float inv = rsqrtf(fmaxf(s, 1e-24f));   // matches max(norm, 1e-12)
        dbuf[3 * k + 0] = dx * inv;
        dbuf[3 * k + 1] = dy * inv;
        dbuf[3 * k + 2] = dz * inv;
    }

    const size_t base = ((size_t)n * (size_t)M + (size_t)m0) * 3;  // multiple of 24 -> 16B-aligned

    // ray_dirs: 6 x 16B stores
    float4* pd = reinterpret_cast<float4*>(out + dir_off + base);
    #pragma unroll
    for (int q = 0; q < 6; ++q)
        pd[q] = make_float4(dbuf[4 * q], dbuf[4 * q + 1], dbuf[4 * q + 2], dbuf[4 * q + 3]);

    // ray_origins: repeating (ox,oy,oz) fp32 pattern, 6 x 16B stores
    const float4 p0 = make_float4(ox, oy, oz, ox);
    const float4 p1 = make_float4(oy, oz, ox, oy);
    const float4 p2 = make_float4(oz, ox, oy, oz);
    float4* po = reinterpret_cast<float4*>(out + base);
    po[0] = p0; po[1] = p1; po[2] = p2;
    po[3] = p0; po[4] = p1; po[5] = p2;
}

extern "C" void kernel_launch(void* const* d_in, const int* in_sizes, int n_in,
                              void* d_out, int out_size, void* d_ws, size_t ws_size,
                              hipStream_t stream) {
    const float* c2w  = (const float*)d_in[0];   // fp32, N x 4 x 4
    const float* intr = (const float*)d_in[1];   // fp32, N x 3 x 3
    float* out = (float*)d_out;                  // fp32

    const int N = in_sizes[0] / 16;                                  // 512/16 = 32
    const long long M = (long long)out_size / (6LL * (long long)N);  // 262144
    const int res = (int)(sqrt((double)M) + 0.5);                    // 512

    const int groups_per_n = (int)(M / 8);               // 32768 threads per camera
    const int blocks_per_n = (groups_per_n + 255) / 256; // 128
    const int grid = N * blocks_per_n;                   // 4096
    const size_t dir_off = (size_t)N * (size_t)M * 3;

    ray_sampler_kernel<<<grid, 256, 0, stream>>>(c2w, intr, out,
                                                 (int)M, res, blocks_per_n, dir_off);
}

// Round 6
// 206.906 us; speedup vs baseline: 1.0670x; 1.0670x over previous
//
#include <hip/hip_runtime.h>
#include <math.h>

// One thread per output float4 (4 consecutive floats of each region).
// Wave store instructions are perfectly lane-contiguous (64 x 16B = 1KB),
// matching the access pattern the harness's 6.65 TB/s fill kernel uses.
// Each float4 spans 2 pixels (3 floats/pixel); both are computed, components
// selected by phase = (4t) % 3.
// out layout: [ray_origins (N*M*3 f32)] [ray_dirs (N*M*3 f32)]
__global__ __launch_bounds__(256) void ray_sampler_contig(
    const float* __restrict__ c2w,   // N*16 fp32, row-major 4x4
    const float* __restrict__ intr,  // N*9 fp32, row-major 3x3
    float* __restrict__ out,
    int F4,            // total float4s per region = N*M*3/4
    int mShift,        // log2(M)
    int resShift,      // log2(res)
    float inv_res,
    size_t dir_off)    // N*M*3 floats
{
    const unsigned t = blockIdx.x * 256u + threadIdx.x;
    if (t >= (unsigned)F4) return;

    const unsigned f0    = t * 4u;        // first float index of this float4
    const unsigned p0    = f0 / 3u;       // first pixel spanned (magic-mul)
    const unsigned phase = f0 - p0 * 3u;  // 0,1,2
    const unsigned Mmask = (1u << mShift) - 1u;
    const unsigned rmask = (1u << resShift) - 1u;

    float d[6], o[6];
    #pragma unroll
    for (int s = 0; s < 2; ++s) {
        const unsigned p = p0 + (unsigned)s;   // p0+1 never exceeds N*M-1 (proven from F4)
        const unsigned n = p >> mShift;
        const unsigned m = p & Mmask;
        const unsigned i = m >> resShift;      // row (y)
        const unsigned j = m & rmask;          // col (x)

        const float* C = c2w + n * 16;
        const float* K = intr + n * 9;

        const float r00 = C[0], r01 = C[1], r02 = C[2];
        const float r10 = C[4], r11 = C[5], r12 = C[6];
        const float r20 = C[8], r21 = C[9], r22 = C[10];
        o[3 * s + 0] = C[3];
        o[3 * s + 1] = C[7];
        o[3 * s + 2] = C[11];

        const float fx = K[0], sk = K[1], cx = K[2];
        const float fy = K[4], cy = K[5];

        const float y_cam  = ((float)i + 0.5f) * inv_res;
        const float ycc    = (y_cam - cy) / fy;
        const float y_lift = -ycc;
        const float xc_off = -cx - sk * ycc;
        const float x_cam  = ((float)j + 0.5f) * inv_res;
        const float x_lift = (x_cam + xc_off) / fx;

        const float dx = fmaf(r00, x_lift, fmaf(r01, y_lift, -r02));
        const float dy = fmaf(r10, x_lift, fmaf(r11, y_lift, -r12));
        const float dz = fmaf(r20, x_lift, fmaf(r21, y_lift, -r22));
        const float ss  = fmaf(dx, dx, fmaf(dy, dy, dz * dz));
        const float inv = rsqrtf(fmaxf(ss, 1e-24f));   // matches max(norm, 1e-12)

        d[3 * s + 0] = dx * inv;
        d[3 * s + 1] = dy * inv;
        d[3 * s + 2] = dz * inv;
    }

    // element e of the float4 is component a[phase + e] of {p0, p0+1}
    float4 vo, vd;
    vo.x = (phase == 0) ? o[0] : ((phase == 1) ? o[1] : o[2]);
    vo.y = (phase == 0) ? o[1] : ((phase == 1) ? o[2] : o[3]);
    vo.z = (phase == 0) ? o[2] : ((phase == 1) ? o[3] : o[4]);
    vo.w = (phase == 0) ? o[3] : ((phase == 1) ? o[4] : o[5]);
    vd.x = (phase == 0) ? d[0] : ((phase == 1) ? d[1] : d[2]);
    vd.y = (phase == 0) ? d[1] : ((phase == 1) ? d[2] : d[3]);
    vd.z = (phase == 0) ? d[2] : ((phase == 1) ? d[3] : d[4]);
    vd.w = (phase == 0) ? d[3] : ((phase == 1) ? d[4] : d[5]);

    reinterpret_cast<float4*>(out)[t]           = vo;  // origins: contiguous 1KB/wave-instr
    reinterpret_cast<float4*>(out + dir_off)[t] = vd;  // dirs:    contiguous 1KB/wave-instr
}

extern "C" void kernel_launch(void* const* d_in, const int* in_sizes, int n_in,
                              void* d_out, int out_size, void* d_ws, size_t ws_size,
                              hipStream_t stream) {
    const float* c2w  = (const float*)d_in[0];   // fp32, N x 4 x 4
    const float* intr = (const float*)d_in[1];   // fp32, N x 3 x 3
    float* out = (float*)d_out;                  // fp32

    const int N = in_sizes[0] / 16;                                  // 32
    const long long M = (long long)out_size / (6LL * (long long)N);  // 262144
    const int res = (int)(sqrt((double)M) + 0.5);                    // 512

    int mShift = 0;   while ((1LL << mShift) < M)  ++mShift;   // 18
    int resShift = 0; while ((1 << resShift) < res) ++resShift; // 9

    const long long F  = (long long)N * M * 3LL;   // floats per region
    const int F4       = (int)(F / 4);             // 6,291,456 float4s
    const int grid     = (F4 + 255) / 256;         // 24,576 blocks
    const size_t dir_off = (size_t)F;

    ray_sampler_contig<<<grid, 256, 0, stream>>>(c2w, intr, out,
                                                 F4, mShift, resShift,
                                                 1.0f / (float)res, dir_off);
}

// Round 7
// 196.744 us; speedup vs baseline: 1.1221x; 1.0517x over previous
//
#include <hip/hip_runtime.h>
#include <math.h>

// Block-uniform camera: each camera's output region is M*3 floats = 196608
// float4s = exactly 768 blocks of 256 threads. So n = blockIdx.x / 768 is
// wave-uniform -> camera constants become s_loads (no per-lane VMEM).
// One thread per float4 of each region; wave stores are perfectly
// lane-contiguous (64 x 16B = 1KB), same pattern as the 6.7 TB/s fill.
// Each float4 spans 2 pixels (3 floats/pixel); phase = (4q) % 3 selects.
// out layout: [ray_origins (N*M*3 f32)] [ray_dirs (N*M*3 f32)]
__global__ __launch_bounds__(256) void ray_sampler_contig(
    const float* __restrict__ c2w,   // N*16 fp32, row-major 4x4
    const float* __restrict__ intr,  // N*9 fp32, row-major 3x3
    float* __restrict__ out,
    int blocks_per_cam,   // (M*3/4) / 256
    int resShift,         // log2(res)
    float inv_res,
    size_t dir_off)       // N*M*3 floats
{
    // wave-uniform camera index
    const unsigned n      = (unsigned)blockIdx.x / (unsigned)blocks_per_cam;
    const unsigned blk    = (unsigned)blockIdx.x - n * (unsigned)blocks_per_cam;
    const unsigned q      = blk * 256u + threadIdx.x;      // float4 idx within camera region
    const unsigned f4_per_cam = (unsigned)blocks_per_cam * 256u;

    const float* C = c2w + n * 16;   // uniform -> s_load
    const float* K = intr + n * 9;   // uniform -> s_load

    const float r00 = C[0], r01 = C[1], r02 = C[2], ox = C[3];
    const float r10 = C[4], r11 = C[5], r12 = C[6], oy = C[7];
    const float r20 = C[8], r21 = C[9], r22 = C[10], oz = C[11];
    const float fx = K[0], sk = K[1], cx = K[2];
    const float fy = K[4], cy = K[5];

    const float inv_fx = 1.0f / fx;   // uniform, once
    const float inv_fy = 1.0f / fy;

    const unsigned f0    = q * 4u;        // float offset within camera region
    const unsigned p0    = f0 / 3u;       // first pixel spanned (magic-mul)
    const unsigned phase = f0 - p0 * 3u;  // 0,1,2
    const unsigned rmask = (1u << resShift) - 1u;

    float d[6];
    #pragma unroll
    for (int s = 0; s < 2; ++s) {
        const unsigned p = p0 + (unsigned)s;   // stays inside this camera (region%4==0)
        const unsigned i = p >> resShift;      // row (y)
        const unsigned j = p & rmask;          // col (x)

        const float y_cam  = ((float)i + 0.5f) * inv_res;
        const float ycc    = (y_cam - cy) * inv_fy;
        const float y_lift = -ycc;
        const float xc_off = -cx - sk * ycc;
        const float x_cam  = ((float)j + 0.5f) * inv_res;
        const float x_lift = (x_cam + xc_off) * inv_fx;

        const float dx = fmaf(r00, x_lift, fmaf(r01, y_lift, -r02));
        const float dy = fmaf(r10, x_lift, fmaf(r11, y_lift, -r12));
        const float dz = fmaf(r20, x_lift, fmaf(r21, y_lift, -r22));
        const float ss  = fmaf(dx, dx, fmaf(dy, dy, dz * dz));
        const float inv = rsqrtf(fmaxf(ss, 1e-24f));   // matches max(norm, 1e-12)

        d[3 * s + 0] = dx * inv;
        d[3 * s + 1] = dy * inv;
        d[3 * s + 2] = dz * inv;
    }

    // origins pattern for this phase (uniform values, per-lane phase)
    const float o[6] = {ox, oy, oz, ox, oy, oz};
    float4 vo, vd;
    vo.x = o[phase + 0]; vo.y = o[phase + 1]; vo.z = o[phase + 2]; vo.w = o[phase + 3];
    vd.x = (phase == 0) ? d[0] : ((phase == 1) ? d[1] : d[2]);
    vd.y = (phase == 0) ? d[1] : ((phase == 1) ? d[2] : d[3]);
    vd.z = (phase == 0) ? d[2] : ((phase == 1) ? d[3] : d[4]);
    vd.w = (phase == 0) ? d[3] : ((phase == 1) ? d[4] : d[5]);

    const size_t t = (size_t)n * f4_per_cam + q;           // global float4 index
    reinterpret_cast<float4*>(out)[t]           = vo;      // origins: contiguous
    reinterpret_cast<float4*>(out + dir_off)[t] = vd;      // dirs:    contiguous
}

extern "C" void kernel_launch(void* const* d_in, const int* in_sizes, int n_in,
                              void* d_out, int out_size, void* d_ws, size_t ws_size,
                              hipStream_t stream) {
    const float* c2w  = (const float*)d_in[0];   // fp32, N x 4 x 4
    const float* intr = (const float*)d_in[1];   // fp32, N x 3 x 3
    float* out = (float*)d_out;                  // fp32

    const int N = in_sizes[0] / 16;                                  // 32
    const long long M = (long long)out_size / (6LL * (long long)N);  // 262144
    const int res = (int)(sqrt((double)M) + 0.5);                    // 512

    int resShift = 0; while ((1 << resShift) < res) ++resShift;      // 9

    const long long F   = (long long)N * M * 3LL;    // floats per region
    const int f4_per_cam = (int)(M * 3LL / 4LL);     // 196608
    const int blocks_per_cam = f4_per_cam / 256;     // 768 (exact)
    const int grid = N * blocks_per_cam;             // 24576
    const size_t dir_off = (size_t)F;

    ray_sampler_contig<<<grid, 256, 0, stream>>>(c2w, intr, out,
                                                 blocks_per_cam, resShift,
                                                 1.0f / (float)res, dir_off);
}